// Round 7
// baseline (2188.613 us; speedup 1.0000x reference)
//
#include <hip/hip_runtime.h>

// JIIF fused pipeline v7 = v6 + (Ycell bf16) + (layer-2 128x256 tile) + merged prep.
// z1 = relu( Yhr[pixel] + Ycell[cell(pixel,k)] + rel*w1rel + b1 )
//   Yhr  = hr_guide_row @ (W1[128:256]+W1[256:384])   (per pixel, bf16 GEMM)
//   Ycell= [feat | -lr] @ W1[[0:128],[256:384]]        (per low-res cell, bf16)
// Layers 2,3 bf16 GEMMs; layer-4 GEMM fuses layer-5 dot + softmax (MODE 2).
// NOTE (R4/R5): 8-wave fused 3+4 tail spills (VGPR pinned at 60, 556 MB scratch
// writes) regardless of launch_bounds; do not resurrect.

typedef unsigned short u16;
typedef unsigned int   u32;
typedef __bf16  bf16x8 __attribute__((ext_vector_type(8)));
typedef float   f32x4  __attribute__((ext_vector_type(4)));
typedef unsigned short u16x8 __attribute__((ext_vector_type(8)));
typedef unsigned short u16x4 __attribute__((ext_vector_type(4)));

__device__ __forceinline__ u16 f2bf(float f) {
  u32 u = __float_as_uint(f);
  u32 r = (u + 0x7FFFu + ((u >> 16) & 1u)) >> 16;   // RNE
  return (u16)r;
}
__device__ __forceinline__ float bf2f(u16 v) {
  return __uint_as_float(((u32)v) << 16);
}
__device__ __forceinline__ void gload_lds16(const void* g, void* l) {
  __builtin_amdgcn_global_load_lds(
      (const __attribute__((address_space(1))) void*)g,
      (__attribute__((address_space(3))) void*)l, 16, 0, 0);
}

// ---------------------------------------------------------------------------
// gather_hr: per-pixel Xhr row (q_guide_hr, bf16[128]) + cellidx[pix][4] + rel[pix][4][2]
// ---------------------------------------------------------------------------
__global__ __launch_bounds__(256)
void gather_hr(const float* __restrict__ coord, const float* __restrict__ hr,
               u16* __restrict__ Xhr, int* __restrict__ cellidx, float* __restrict__ rel)
{
  __shared__ u16 hrT[64 * 130];
  __shared__ int nhrS[64];

  const int tid = threadIdx.x;
  const int pb  = blockIdx.x << 6;        // global pixel base
  const int b   = pb >> 16;
  const int n0  = pb & 65535;
  const float rh = 0.015625f;             // 1/64

  if (tid < 64) {
    const int n = n0 + tid;
    const float cy = coord[(size_t)(b * 65536 + n) * 2 + 0];
    const float cx = coord[(size_t)(b * 65536 + n) * 2 + 1];
    float fyh = (cy + 1.0f) * 128.0f - 0.5f;
    float fxh = (cx + 1.0f) * 128.0f - 0.5f;
    int iyh = (int)floorf(fyh + 0.5f);
    int ixh = (int)floorf(fxh + 0.5f);
    bool vh = (iyh >= 0 && iyh < 256 && ixh >= 0 && ixh < 256);
    nhrS[tid] = vh ? ((iyh << 8) + ixh) : -1;
#pragma unroll
    for (int k = 0; k < 4; ++k) {
      const float vx = (k < 2) ? -1.0f : 1.0f;
      const float vy = (k & 1) ? 1.0f : -1.0f;
      const float cyk = cy + vx * rh;
      const float cxk = cx + vy * rh;
      float fy = (cyk + 1.0f) * 32.0f - 0.5f;
      float fx = (cxk + 1.0f) * 32.0f - 0.5f;
      int iy = (int)floorf(fy + 0.5f);
      int ix = (int)floorf(fx + 0.5f);
      bool valid = (iy >= 0 && iy < 64 && ix >= 0 && ix < 64);
      int iyc = min(max(iy, 0), 63);
      int ixc = min(max(ix, 0), 63);
      float qy = valid ? ((-1.0f + rh) + (2.0f * rh) * (float)iyc) : 0.0f;
      float qx = valid ? ((-1.0f + rh) + (2.0f * rh) * (float)ixc) : 0.0f;
      const int p4 = ((pb + tid) << 2) + k;
      rel[2 * p4 + 0] = (cy - qy) * 64.0f;
      rel[2 * p4 + 1] = (cx - qx) * 64.0f;
      cellidx[p4] = valid ? (b * 4096 + iyc * 64 + ixc) : -1;
    }
  }
  __syncthreads();

  const size_t hb = (size_t)b * 128 * 65536;
  for (int e = tid; e < 64 * 128; e += 256) {
    const int pix = e & 63, c = e >> 6;
    const int n = nhrS[pix];
    const float v = (n >= 0) ? hr[hb + (size_t)c * 65536 + n] : 0.0f;
    hrT[pix * 130 + c] = f2bf(v);
  }
  __syncthreads();

  for (int e = tid; e < 64 * 128; e += 256) {
    const int pix = e >> 7, c = e & 127;
    Xhr[(size_t)(pb + pix) * 128 + c] = hrT[pix * 130 + c];
  }
}

// ---------------------------------------------------------------------------
// prep_cells: Xcell[cell][0:128]=feat, [128:256]=-lr  (bf16)
// ---------------------------------------------------------------------------
__global__ __launch_bounds__(256)
void prep_cells(const float* __restrict__ feat, const float* __restrict__ lr,
                u16* __restrict__ Xcell)
{
  __shared__ u16 t[64 * 258];
  const int tid = threadIdx.x;
  const int cb = blockIdx.x << 6;
  const int b = cb >> 12;
  const int local = cb & 4095;
  const size_t fb = (size_t)b * 128 * 4096;
  for (int e = tid; e < 64 * 128; e += 256) {
    const int cell = e & 63, c = e >> 6;
    const size_t idx = fb + (size_t)c * 4096 + local + cell;
    t[cell * 258 + c]       = f2bf(feat[idx]);
    t[cell * 258 + 128 + c] = (u16)(f2bf(lr[idx]) ^ 0x8000u);
  }
  __syncthreads();
  for (int e = tid; e < 64 * 256; e += 256) {
    const int cell = e >> 8, c = e & 255;
    Xcell[(size_t)(cb + cell) * 256 + c] = t[cell * 258 + c];
  }
}

// ---------------------------------------------------------------------------
// bf16 MFMA GEMM; BK=64 per iteration via two 32-k LDS slabs; 128 x BN tile
// (BN = 128 or 256). LDS k-chunk XOR swizzle + XCD-aware block mapping.
// MODE 0: C bf16 = relu(A@B^T + bias)
// MODE 2: BN==128, N==128; relu(A@B^T+bias) -> LDS tile -> layer5 dot+softmax -> out
// MODE 3: C bf16 = A@B^T (raw)
// K must be a multiple of 64; M mult of 128; N mult of BN.
// ---------------------------------------------------------------------------
template<int MODE, int BN = 128>
__global__ __launch_bounds__(256)
void gemm_bt(const u16* __restrict__ A, const u16* __restrict__ BT,
             void* __restrict__ Cout, const float* __restrict__ bias,
             int M, int N, int K,
             const float* __restrict__ w5, const float* __restrict__ b5,
             float* __restrict__ outp, int gp0)
{
  constexpr int NJ = BN >> 5;                 // jj count per wave
  // sh: As slabs [0,8192) u16; Bs slabs [8192, 8192+2*BN*32).
  // MODE2 (BN=128) reuses sh as a 128x136 u16 tile after the K-loop.
  __shared__ __align__(16) u16 sh[(MODE == 2) ? 17408 : (8192 + (BN << 6))];
  u16* As = sh;
  u16* Bs = sh + 8192;

  const int tid = threadIdx.x;
  const int w = tid >> 6;
  const int lane = tid & 63;
  const int ntn = N / BN;
  const int nmt = M >> 7;
  int bm, bn;
  if ((nmt & 7) == 0) {
    const int xcd = blockIdx.x & 7;
    const int t = blockIdx.x >> 3;
    bn = t % ntn;
    bm = xcd * (nmt >> 3) + t / ntn;
  } else {
    bm = blockIdx.x / ntn;
    bn = blockIdx.x - bm * ntn;
  }
  const int m0 = bm << 7, n0 = bn * BN;

  const int lrow = tid >> 2;                 // 0..63 staging row (per q-group)
  const int cc   = tid & 3;                  // physical 16B chunk within row
  const int gcol = (cc ^ ((lrow >> 1) & 3)) << 3;

  f32x4 acc[4][NJ];
#pragma unroll
  for (int ii = 0; ii < 4; ++ii)
#pragma unroll
    for (int jj = 0; jj < NJ; ++jj)
      acc[ii][jj] = f32x4{0.f, 0.f, 0.f, 0.f};

  const int mbase = (w & 1) << 6;
  const int nbase = (w >> 1) * (BN >> 1);
  const int fr = lane & 15;
  const int fq = lane >> 4;
  const int rchunk = (fq ^ ((fr >> 1) & 3)) << 3;

  for (int kt = 0; kt < K; kt += 64) {
#pragma unroll
    for (int s = 0; s < 2; ++s) {
      const int kb = kt + (s << 5);
#pragma unroll
      for (int q = 0; q < 2; ++q) {
        const int mrow = (q << 6) + lrow;
        gload_lds16(A + (size_t)(m0 + mrow) * K + (kb + gcol),
                    (char*)As + (s << 13) + (q << 12) + (w << 10));
      }
#pragma unroll
      for (int q = 0; q < (BN >> 6); ++q) {
        const int nrow = (q << 6) + lrow;
        gload_lds16(BT + (size_t)(n0 + nrow) * K + (kb + gcol),
                    (char*)Bs + s * (BN << 6) + (q << 12) + (w << 10));
      }
    }
    __syncthreads();
#pragma unroll
    for (int s = 0; s < 2; ++s) {
      const int soA = s << 12;                // u16 offset of As slab
      const int soB = s * (BN << 5);          // u16 offset of Bs slab
      bf16x8 af[4], bfv[NJ];
#pragma unroll
      for (int ii = 0; ii < 4; ++ii)
        af[ii] = *(const bf16x8*)(As + soA + ((mbase + (ii << 4) + fr) << 5) + rchunk);
#pragma unroll
      for (int jj = 0; jj < NJ; ++jj)
        bfv[jj] = *(const bf16x8*)(Bs + soB + ((nbase + (jj << 4) + fr) << 5) + rchunk);
#pragma unroll
      for (int ii = 0; ii < 4; ++ii)
#pragma unroll
        for (int jj = 0; jj < NJ; ++jj)
          acc[ii][jj] = __builtin_amdgcn_mfma_f32_16x16x32_bf16(af[ii], bfv[jj], acc[ii][jj], 0, 0, 0);
    }
    __syncthreads();
  }

  if constexpr (MODE == 2) {
    // ---- fused layer-4 epilogue + layer-5 blend (N == 128, BN == 128) ----
#pragma unroll
    for (int jj = 0; jj < 4; ++jj) {
      const int col = nbase + (jj << 4) + fr;
      const float bi = bias[col];
#pragma unroll
      for (int ii = 0; ii < 4; ++ii) {
#pragma unroll
        for (int r = 0; r < 4; ++r) {
          const int row = mbase + (ii << 4) + (fq << 2) + r;
          sh[row * 136 + col] = f2bf(fmaxf(acc[ii][jj][r] + bi, 0.f));
        }
      }
    }
    const int cbase = fr << 3;
    float w50[8], w51[8];
#pragma unroll
    for (int j = 0; j < 8; ++j) {
      w50[j] = w5[((cbase + j) << 1) + 0];
      w51[j] = w5[((cbase + j) << 1) + 1];
    }
    const float b50 = b5[0], b51 = b5[1];
    __syncthreads();
#pragma unroll
    for (int rep = 0; rep < 8; ++rep) {
      const int pl = w + (rep << 2);              // block-local pixel 0..31
      const int row = (pl << 2) + fq;             // branch k = fq
      const u16x8 v = *(const u16x8*)(sh + row * 136 + cbase);
      float s0 = 0.f, s1 = 0.f;
#pragma unroll
      for (int j = 0; j < 8; ++j) {
        const float a = bf2f(v[j]);
        s0 += a * w50[j];
        s1 += a * w51[j];
      }
#pragma unroll
      for (int off = 8; off >= 1; off >>= 1) {
        s0 += __shfl_xor(s0, off, 16);
        s1 += __shfl_xor(s1, off, 16);
      }
      float p0[4], p1[4];
#pragma unroll
      for (int k = 0; k < 4; ++k) {
        p0[k] = __shfl(s0, k << 4, 64) + b50;
        p1[k] = __shfl(s1, k << 4, 64) + b51;
      }
      if (lane == 0) {
        float mx = fmaxf(fmaxf(p1[0], p1[1]), fmaxf(p1[2], p1[3]));
        float e0 = expf(p1[0] - mx), e1 = expf(p1[1] - mx);
        float e2 = expf(p1[2] - mx), e3 = expf(p1[3] - mx);
        outp[gp0 + (m0 >> 2) + pl] =
            (p0[0] * e0 + p0[1] * e1 + p0[2] * e2 + p0[3] * e3) / (e0 + e1 + e2 + e3);
      }
    }
  } else {
#pragma unroll
    for (int jj = 0; jj < NJ; ++jj) {
      const int ncol = n0 + nbase + (jj << 4) + fr;
      const float bi = (MODE == 0) ? bias[ncol] : 0.f;
#pragma unroll
      for (int ii = 0; ii < 4; ++ii) {
#pragma unroll
        for (int r = 0; r < 4; ++r) {
          const int mrow = m0 + mbase + (ii << 4) + (fq << 2) + r;
          if (MODE == 0) {
            ((u16*)Cout)[(size_t)mrow * N + ncol] = f2bf(fmaxf(acc[ii][jj][r] + bi, 0.f));
          } else {  // MODE 3
            ((u16*)Cout)[(size_t)mrow * N + ncol] = f2bf(acc[ii][jj][r]);
          }
        }
      }
    }
  }
}

// ---------------------------------------------------------------------------
// expand_a1: wave per pixel. A1[(p*4+k)][c] = relu(Yhr[p][c] + b1[c] +
//            Ycell[cell[k]][c] + ry*w1rel0[c] + rx*w1rel1[c]); Ycell is bf16.
// ---------------------------------------------------------------------------
__global__ __launch_bounds__(256)
void expand_a1(const u16* __restrict__ Yhr, const u16* __restrict__ Ycell,
               const float* __restrict__ b1, const float* __restrict__ w1rel,
               const int* __restrict__ cellidx, const float* __restrict__ rel,
               u16* __restrict__ A1, int gp0)
{
  const int lane = threadIdx.x & 63;
  const int wv = threadIdx.x >> 6;
  const int p = (blockIdx.x << 2) + wv;        // chunk-local pixel
  const int gpix = gp0 + p;

  const int4   civ = *(const int4*)(cellidx + (size_t)gpix * 4);
  const float4 ra  = *(const float4*)(rel + (size_t)gpix * 8);
  const float4 rb  = *(const float4*)(rel + (size_t)gpix * 8 + 4);
  const int   cis[4] = {civ.x, civ.y, civ.z, civ.w};
  const float ry[4]  = {ra.x, ra.z, rb.x, rb.z};
  const float rx[4]  = {ra.y, ra.w, rb.y, rb.w};

#pragma unroll
  for (int s = 0; s < 2; ++s) {
    const int col = (s << 9) + (lane << 3);    // 8 cols per lane
    const u16x8 yh = *(const u16x8*)(Yhr + (size_t)p * 1024 + col);
    float base[8], w0[8], w1v[8];
#pragma unroll
    for (int h = 0; h < 2; ++h) {
      const float4 bv = *(const float4*)(b1 + col + (h << 2));
      const float4 a0 = *(const float4*)(w1rel + col + (h << 2));
      const float4 a1 = *(const float4*)(w1rel + 1024 + col + (h << 2));
      base[h * 4 + 0] = bv.x; base[h * 4 + 1] = bv.y;
      base[h * 4 + 2] = bv.z; base[h * 4 + 3] = bv.w;
      w0[h * 4 + 0] = a0.x; w0[h * 4 + 1] = a0.y; w0[h * 4 + 2] = a0.z; w0[h * 4 + 3] = a0.w;
      w1v[h * 4 + 0] = a1.x; w1v[h * 4 + 1] = a1.y; w1v[h * 4 + 2] = a1.z; w1v[h * 4 + 3] = a1.w;
    }
#pragma unroll
    for (int j = 0; j < 8; ++j) base[j] += bf2f(yh[j]);
#pragma unroll
    for (int k = 0; k < 4; ++k) {
      u16x8 yc = {0, 0, 0, 0, 0, 0, 0, 0};
      if (cis[k] >= 0) yc = *(const u16x8*)(Ycell + (size_t)cis[k] * 1024 + col);
      u16x8 o;
#pragma unroll
      for (int j = 0; j < 8; ++j)
        o[j] = f2bf(fmaxf(base[j] + bf2f(yc[j]) + ry[k] * w0[j] + rx[k] * w1v[j], 0.f));
      *(u16x8*)(A1 + (size_t)((p << 2) + k) * 1024 + col) = o;
    }
  }
}

// ---------------------------------------------------------------------------
// prep_all: all transposed bf16 weights in one dispatch.
// ranges: [0,131072) W1hrT[1024][128]; [.,393216) W1cellT[1024][256];
//         [.,917504) W2T[512][1024]; [.,1048576) W3T[256][512]; [.,1081344) W4T[128][256]
// ---------------------------------------------------------------------------
__global__ __launch_bounds__(256)
void prep_all(const float* __restrict__ w1, const float* __restrict__ w2,
              const float* __restrict__ w3, const float* __restrict__ w4,
              u16* __restrict__ W1hrT, u16* __restrict__ W1cellT,
              u16* __restrict__ W2T, u16* __restrict__ W3T, u16* __restrict__ W4T)
{
  const int idx = blockIdx.x * 256 + threadIdx.x;
  if (idx < 131072) {
    const int n = idx >> 7, k = idx & 127;
    W1hrT[idx] = f2bf(w1[(128 + k) * 1024 + n] + w1[(256 + k) * 1024 + n]);
  } else if (idx < 393216) {
    const int i = idx - 131072;
    const int n = i >> 8, k = i & 255;
    W1cellT[i] = f2bf((k < 128) ? w1[k * 1024 + n] : w1[(128 + k) * 1024 + n]);
  } else if (idx < 917504) {
    const int i = idx - 393216;
    const int n = i >> 10, k = i & 1023;
    W2T[i] = f2bf(w2[k * 512 + n]);
  } else if (idx < 1048576) {
    const int i = idx - 917504;
    const int n = i >> 9, k = i & 511;
    W3T[i] = f2bf(w3[k * 256 + n]);
  } else if (idx < 1081344) {
    const int i = idx - 1048576;
    const int n = i >> 8, k = i & 255;
    W4T[i] = f2bf(w4[k * 128 + n]);
  }
}

// ---------------------------------------------------------------------------
extern "C" void kernel_launch(void* const* d_in, const int* in_sizes, int n_in,
                              void* d_out, int out_size, void* d_ws, size_t ws_size,
                              hipStream_t stream)
{
  const float* feat  = (const float*)d_in[0];
  const float* coord = (const float*)d_in[1];
  const float* hrg   = (const float*)d_in[2];
  const float* lrg   = (const float*)d_in[3];
  const float* w1 = (const float*)d_in[4];
  const float* b1 = (const float*)d_in[5];
  const float* w2 = (const float*)d_in[6];
  const float* b2 = (const float*)d_in[7];
  const float* w3 = (const float*)d_in[8];
  const float* b3 = (const float*)d_in[9];
  const float* w4 = (const float*)d_in[10];
  const float* b4 = (const float*)d_in[11];
  const float* w5 = (const float*)d_in[12];
  const float* b5 = (const float*)d_in[13];
  float* out = (float*)d_out;

  char* base = (char*)d_ws;
  u16* W1hrT   = (u16*)base;                       // [1024][128]
  u16* W1cellT = W1hrT + 1024 * 128;               // [1024][256]
  u16* W2T     = W1cellT + 1024 * 256;             // [512][1024]
  u16* W3T     = W2T + 512 * 1024;                 // [256][512]
  u16* W4T     = W3T + 256 * 512;                  // [128][256]
  u16* Xcell   = W4T + 128 * 256;                  // [8192][256]
  u16* Ycell   = Xcell + 8192 * 256;               // [8192][1024] bf16
  u16* Xhr     = Ycell + (size_t)8192 * 1024;      // [131072][128]
  float* relb  = (float*)(Xhr + (size_t)131072 * 128); // [131072][4][2]
  int* cellidx = (int*)(relb + (size_t)131072 * 8);    // [131072][4]
  char* chunk_base = (char*)(cellidx + (size_t)131072 * 4);
  const size_t fixed = (size_t)(chunk_base - base);

  const int NP = 131072;
  // per-pixel chunk bytes: Yhr/A3 2048 + A1 8192 + A2 4096 = 14336 (A3 aliases Yhr)
  int nc = 1;
  while (nc < 128 && fixed + (size_t)(NP / nc) * 14336ULL > ws_size) nc <<= 1;
  const int CP = NP / nc;
  const int R = CP * 4;

  u16* Yhr = (u16*)chunk_base;          // [CP][1024] bf16 ; later A3 [R][256] bf16
  u16* A1  = Yhr + (size_t)CP * 1024;   // [R][1024] bf16
  u16* A2  = A1 + (size_t)R * 1024;     // [R][512] bf16
  u16* A3  = Yhr;                       // alias (Yhr dead after expand_a1)

  prep_all<<<4224, 256, 0, stream>>>(w1, w2, w3, w4, W1hrT, W1cellT, W2T, W3T, W4T);
  gather_hr<<<NP / 64, 256, 0, stream>>>(coord, hrg, Xhr, cellidx, relb);
  prep_cells<<<8192 / 64, 256, 0, stream>>>(feat, lrg, Xcell);
  // Ycell = Xcell @ W1cellT^T (raw bf16)
  gemm_bt<3><<<(8192 / 128) * (1024 / 128), 256, 0, stream>>>(
      Xcell, W1cellT, (void*)Ycell, nullptr, 8192, 1024, 256,
      nullptr, nullptr, nullptr, 0);

  for (int ch = 0; ch < nc; ++ch) {
    const int gp0 = ch * CP;
    // Yhr = Xhr_chunk @ W1hrT^T (raw bf16)
    gemm_bt<3><<<(CP / 128) * (1024 / 128), 256, 0, stream>>>(
        Xhr + (size_t)gp0 * 128, W1hrT, (void*)Yhr, nullptr, CP, 1024, 128,
        nullptr, nullptr, nullptr, 0);
    expand_a1<<<CP / 4, 256, 0, stream>>>(
        Yhr, Ycell, b1, w1 + 384 * 1024, cellidx, relb, A1, gp0);
    // layer-2: 128x256 tile
    gemm_bt<0, 256><<<(R / 128) * (512 / 256), 256, 0, stream>>>(
        A1, W2T, (void*)A2, b2, R, 512, 1024, nullptr, nullptr, nullptr, 0);
    gemm_bt<0><<<(R / 128) * (256 / 128), 256, 0, stream>>>(
        A2, W3T, (void*)A3, b3, R, 256, 512, nullptr, nullptr, nullptr, 0);
    gemm_bt<2><<<(R / 128) * (128 / 128), 256, 0, stream>>>(
        A3, W4T, nullptr, b4, R, 128, 256, w5, b5, out, gp0);
  }
}

// Round 8
// 1765.405 us; speedup vs baseline: 1.2397x; 1.2397x over previous
//
#include <hip/hip_runtime.h>

// JIIF fused pipeline v8 = v7 with layer-2 reverted to 128x128 tile.
// z1 = relu( Yhr[pixel] + Ycell[cell(pixel,k)] + rel*w1rel + b1 )
//   Yhr  = hr_guide_row @ (W1[128:256]+W1[256:384])   (per pixel, bf16 GEMM)
//   Ycell= [feat | -lr] @ W1[[0:128],[256:384]]        (per low-res cell, bf16)
// Layers 2,3 bf16 GEMMs; layer-4 GEMM fuses layer-5 dot + softmax (MODE 2).
// NOTES:
//  - R4/R5: 8-wave fused 3+4 tail spills (VGPR pinned at 60, 556 MB scratch
//    writes) regardless of launch_bounds; do not resurrect.
//  - R7: layer-2 at 128x256 (BN=256) REGRESSED 52->95 us: grid 512 blocks
//    (2/CU) + 48 KB LDS + 160 VGPR -> occupancy collapse (18->11%),
//    MfmaUtil 25->14%. Keep BN=128 for K=1024/N=512 shapes.

typedef unsigned short u16;
typedef unsigned int   u32;
typedef __bf16  bf16x8 __attribute__((ext_vector_type(8)));
typedef float   f32x4  __attribute__((ext_vector_type(4)));
typedef unsigned short u16x8 __attribute__((ext_vector_type(8)));
typedef unsigned short u16x4 __attribute__((ext_vector_type(4)));

__device__ __forceinline__ u16 f2bf(float f) {
  u32 u = __float_as_uint(f);
  u32 r = (u + 0x7FFFu + ((u >> 16) & 1u)) >> 16;   // RNE
  return (u16)r;
}
__device__ __forceinline__ float bf2f(u16 v) {
  return __uint_as_float(((u32)v) << 16);
}
__device__ __forceinline__ void gload_lds16(const void* g, void* l) {
  __builtin_amdgcn_global_load_lds(
      (const __attribute__((address_space(1))) void*)g,
      (__attribute__((address_space(3))) void*)l, 16, 0, 0);
}

// ---------------------------------------------------------------------------
// gather_hr: per-pixel Xhr row (q_guide_hr, bf16[128]) + cellidx[pix][4] + rel[pix][4][2]
// ---------------------------------------------------------------------------
__global__ __launch_bounds__(256)
void gather_hr(const float* __restrict__ coord, const float* __restrict__ hr,
               u16* __restrict__ Xhr, int* __restrict__ cellidx, float* __restrict__ rel)
{
  __shared__ u16 hrT[64 * 130];
  __shared__ int nhrS[64];

  const int tid = threadIdx.x;
  const int pb  = blockIdx.x << 6;        // global pixel base
  const int b   = pb >> 16;
  const int n0  = pb & 65535;
  const float rh = 0.015625f;             // 1/64

  if (tid < 64) {
    const int n = n0 + tid;
    const float cy = coord[(size_t)(b * 65536 + n) * 2 + 0];
    const float cx = coord[(size_t)(b * 65536 + n) * 2 + 1];
    float fyh = (cy + 1.0f) * 128.0f - 0.5f;
    float fxh = (cx + 1.0f) * 128.0f - 0.5f;
    int iyh = (int)floorf(fyh + 0.5f);
    int ixh = (int)floorf(fxh + 0.5f);
    bool vh = (iyh >= 0 && iyh < 256 && ixh >= 0 && ixh < 256);
    nhrS[tid] = vh ? ((iyh << 8) + ixh) : -1;
#pragma unroll
    for (int k = 0; k < 4; ++k) {
      const float vx = (k < 2) ? -1.0f : 1.0f;
      const float vy = (k & 1) ? 1.0f : -1.0f;
      const float cyk = cy + vx * rh;
      const float cxk = cx + vy * rh;
      float fy = (cyk + 1.0f) * 32.0f - 0.5f;
      float fx = (cxk + 1.0f) * 32.0f - 0.5f;
      int iy = (int)floorf(fy + 0.5f);
      int ix = (int)floorf(fx + 0.5f);
      bool valid = (iy >= 0 && iy < 64 && ix >= 0 && ix < 64);
      int iyc = min(max(iy, 0), 63);
      int ixc = min(max(ix, 0), 63);
      float qy = valid ? ((-1.0f + rh) + (2.0f * rh) * (float)iyc) : 0.0f;
      float qx = valid ? ((-1.0f + rh) + (2.0f * rh) * (float)ixc) : 0.0f;
      const int p4 = ((pb + tid) << 2) + k;
      rel[2 * p4 + 0] = (cy - qy) * 64.0f;
      rel[2 * p4 + 1] = (cx - qx) * 64.0f;
      cellidx[p4] = valid ? (b * 4096 + iyc * 64 + ixc) : -1;
    }
  }
  __syncthreads();

  const size_t hb = (size_t)b * 128 * 65536;
  for (int e = tid; e < 64 * 128; e += 256) {
    const int pix = e & 63, c = e >> 6;
    const int n = nhrS[pix];
    const float v = (n >= 0) ? hr[hb + (size_t)c * 65536 + n] : 0.0f;
    hrT[pix * 130 + c] = f2bf(v);
  }
  __syncthreads();

  for (int e = tid; e < 64 * 128; e += 256) {
    const int pix = e >> 7, c = e & 127;
    Xhr[(size_t)(pb + pix) * 128 + c] = hrT[pix * 130 + c];
  }
}

// ---------------------------------------------------------------------------
// prep_cells: Xcell[cell][0:128]=feat, [128:256]=-lr  (bf16)
// ---------------------------------------------------------------------------
__global__ __launch_bounds__(256)
void prep_cells(const float* __restrict__ feat, const float* __restrict__ lr,
                u16* __restrict__ Xcell)
{
  __shared__ u16 t[64 * 258];
  const int tid = threadIdx.x;
  const int cb = blockIdx.x << 6;
  const int b = cb >> 12;
  const int local = cb & 4095;
  const size_t fb = (size_t)b * 128 * 4096;
  for (int e = tid; e < 64 * 128; e += 256) {
    const int cell = e & 63, c = e >> 6;
    const size_t idx = fb + (size_t)c * 4096 + local + cell;
    t[cell * 258 + c]       = f2bf(feat[idx]);
    t[cell * 258 + 128 + c] = (u16)(f2bf(lr[idx]) ^ 0x8000u);
  }
  __syncthreads();
  for (int e = tid; e < 64 * 256; e += 256) {
    const int cell = e >> 8, c = e & 255;
    Xcell[(size_t)(cb + cell) * 256 + c] = t[cell * 258 + c];
  }
}

// ---------------------------------------------------------------------------
// bf16 MFMA GEMM; BK=64 per iteration via two 32-k LDS slabs; 128x128 tile.
// LDS k-chunk XOR swizzle + XCD-aware block mapping.
// MODE 0: C bf16 = relu(A@B^T + bias)
// MODE 2: N==128; relu(A@B^T+bias) -> LDS tile -> layer5 dot+softmax -> out
// MODE 3: C bf16 = A@B^T (raw)
// K must be a multiple of 64; M mult of 128; N mult of 128.
// ---------------------------------------------------------------------------
template<int MODE>
__global__ __launch_bounds__(256)
void gemm_bt(const u16* __restrict__ A, const u16* __restrict__ BT,
             void* __restrict__ Cout, const float* __restrict__ bias,
             int M, int N, int K,
             const float* __restrict__ w5, const float* __restrict__ b5,
             float* __restrict__ outp, int gp0)
{
  // sh: As slabs [0,8192) u16; Bs slabs [8192,16384).
  // MODE2 reuses sh as a 128x136 u16 tile after the K-loop.
  __shared__ __align__(16) u16 sh[(MODE == 2) ? 17408 : 16384];
  u16* As = sh;
  u16* Bs = sh + 8192;

  const int tid = threadIdx.x;
  const int w = tid >> 6;
  const int lane = tid & 63;
  const int ntn = N >> 7;
  const int nmt = M >> 7;
  int bm, bn;
  if ((nmt & 7) == 0) {
    const int xcd = blockIdx.x & 7;
    const int t = blockIdx.x >> 3;
    bn = t % ntn;
    bm = xcd * (nmt >> 3) + t / ntn;
  } else {
    bm = blockIdx.x / ntn;
    bn = blockIdx.x - bm * ntn;
  }
  const int m0 = bm << 7, n0 = bn << 7;

  const int lrow = tid >> 2;                 // 0..63 staging row (per q-group)
  const int cc   = tid & 3;                  // physical 16B chunk within row
  const int gcol = (cc ^ ((lrow >> 1) & 3)) << 3;

  f32x4 acc[4][4];
#pragma unroll
  for (int ii = 0; ii < 4; ++ii)
#pragma unroll
    for (int jj = 0; jj < 4; ++jj)
      acc[ii][jj] = f32x4{0.f, 0.f, 0.f, 0.f};

  const int mbase = (w & 1) << 6;
  const int nbase = (w >> 1) << 6;
  const int fr = lane & 15;
  const int fq = lane >> 4;
  const int rchunk = (fq ^ ((fr >> 1) & 3)) << 3;

  for (int kt = 0; kt < K; kt += 64) {
#pragma unroll
    for (int s = 0; s < 2; ++s) {
      const int kb = kt + (s << 5);
#pragma unroll
      for (int q = 0; q < 2; ++q) {
        const int mrow = (q << 6) + lrow;
        gload_lds16(A + (size_t)(m0 + mrow) * K + (kb + gcol),
                    (char*)As + (s << 13) + (q << 12) + (w << 10));
        gload_lds16(BT + (size_t)(n0 + mrow) * K + (kb + gcol),
                    (char*)Bs + (s << 13) + (q << 12) + (w << 10));
      }
    }
    __syncthreads();
#pragma unroll
    for (int s = 0; s < 2; ++s) {
      const int so = s << 12;                // u16 offset of slab
      bf16x8 af[4], bfv[4];
#pragma unroll
      for (int ii = 0; ii < 4; ++ii) {
        af[ii]  = *(const bf16x8*)(As + so + ((mbase + (ii << 4) + fr) << 5) + rchunk);
        bfv[ii] = *(const bf16x8*)(Bs + so + ((nbase + (ii << 4) + fr) << 5) + rchunk);
      }
#pragma unroll
      for (int ii = 0; ii < 4; ++ii)
#pragma unroll
        for (int jj = 0; jj < 4; ++jj)
          acc[ii][jj] = __builtin_amdgcn_mfma_f32_16x16x32_bf16(af[ii], bfv[jj], acc[ii][jj], 0, 0, 0);
    }
    __syncthreads();
  }

  if constexpr (MODE == 2) {
    // ---- fused layer-4 epilogue + layer-5 blend (N == 128) ----
#pragma unroll
    for (int jj = 0; jj < 4; ++jj) {
      const int col = nbase + (jj << 4) + fr;
      const float bi = bias[col];
#pragma unroll
      for (int ii = 0; ii < 4; ++ii) {
#pragma unroll
        for (int r = 0; r < 4; ++r) {
          const int row = mbase + (ii << 4) + (fq << 2) + r;
          sh[row * 136 + col] = f2bf(fmaxf(acc[ii][jj][r] + bi, 0.f));
        }
      }
    }
    const int cbase = fr << 3;
    float w50[8], w51[8];
#pragma unroll
    for (int j = 0; j < 8; ++j) {
      w50[j] = w5[((cbase + j) << 1) + 0];
      w51[j] = w5[((cbase + j) << 1) + 1];
    }
    const float b50 = b5[0], b51 = b5[1];
    __syncthreads();
#pragma unroll
    for (int rep = 0; rep < 8; ++rep) {
      const int pl = w + (rep << 2);              // block-local pixel 0..31
      const int row = (pl << 2) + fq;             // branch k = fq
      const u16x8 v = *(const u16x8*)(sh + row * 136 + cbase);
      float s0 = 0.f, s1 = 0.f;
#pragma unroll
      for (int j = 0; j < 8; ++j) {
        const float a = bf2f(v[j]);
        s0 += a * w50[j];
        s1 += a * w51[j];
      }
#pragma unroll
      for (int off = 8; off >= 1; off >>= 1) {
        s0 += __shfl_xor(s0, off, 16);
        s1 += __shfl_xor(s1, off, 16);
      }
      float p0[4], p1[4];
#pragma unroll
      for (int k = 0; k < 4; ++k) {
        p0[k] = __shfl(s0, k << 4, 64) + b50;
        p1[k] = __shfl(s1, k << 4, 64) + b51;
      }
      if (lane == 0) {
        float mx = fmaxf(fmaxf(p1[0], p1[1]), fmaxf(p1[2], p1[3]));
        float e0 = expf(p1[0] - mx), e1 = expf(p1[1] - mx);
        float e2 = expf(p1[2] - mx), e3 = expf(p1[3] - mx);
        outp[gp0 + (m0 >> 2) + pl] =
            (p0[0] * e0 + p0[1] * e1 + p0[2] * e2 + p0[3] * e3) / (e0 + e1 + e2 + e3);
      }
    }
  } else {
#pragma unroll
    for (int jj = 0; jj < 4; ++jj) {
      const int ncol = n0 + nbase + (jj << 4) + fr;
      const float bi = (MODE == 0) ? bias[ncol] : 0.f;
#pragma unroll
      for (int ii = 0; ii < 4; ++ii) {
#pragma unroll
        for (int r = 0; r < 4; ++r) {
          const int mrow = m0 + mbase + (ii << 4) + (fq << 2) + r;
          if (MODE == 0) {
            ((u16*)Cout)[(size_t)mrow * N + ncol] = f2bf(fmaxf(acc[ii][jj][r] + bi, 0.f));
          } else {  // MODE 3
            ((u16*)Cout)[(size_t)mrow * N + ncol] = f2bf(acc[ii][jj][r]);
          }
        }
      }
    }
  }
}

// ---------------------------------------------------------------------------
// expand_a1: wave per pixel. A1[(p*4+k)][c] = relu(Yhr[p][c] + b1[c] +
//            Ycell[cell[k]][c] + ry*w1rel0[c] + rx*w1rel1[c]); Ycell is bf16.
// ---------------------------------------------------------------------------
__global__ __launch_bounds__(256)
void expand_a1(const u16* __restrict__ Yhr, const u16* __restrict__ Ycell,
               const float* __restrict__ b1, const float* __restrict__ w1rel,
               const int* __restrict__ cellidx, const float* __restrict__ rel,
               u16* __restrict__ A1, int gp0)
{
  const int lane = threadIdx.x & 63;
  const int wv = threadIdx.x >> 6;
  const int p = (blockIdx.x << 2) + wv;        // chunk-local pixel
  const int gpix = gp0 + p;

  const int4   civ = *(const int4*)(cellidx + (size_t)gpix * 4);
  const float4 ra  = *(const float4*)(rel + (size_t)gpix * 8);
  const float4 rb  = *(const float4*)(rel + (size_t)gpix * 8 + 4);
  const int   cis[4] = {civ.x, civ.y, civ.z, civ.w};
  const float ry[4]  = {ra.x, ra.z, rb.x, rb.z};
  const float rx[4]  = {ra.y, ra.w, rb.y, rb.w};

#pragma unroll
  for (int s = 0; s < 2; ++s) {
    const int col = (s << 9) + (lane << 3);    // 8 cols per lane
    const u16x8 yh = *(const u16x8*)(Yhr + (size_t)p * 1024 + col);
    float base[8], w0[8], w1v[8];
#pragma unroll
    for (int h = 0; h < 2; ++h) {
      const float4 bv = *(const float4*)(b1 + col + (h << 2));
      const float4 a0 = *(const float4*)(w1rel + col + (h << 2));
      const float4 a1 = *(const float4*)(w1rel + 1024 + col + (h << 2));
      base[h * 4 + 0] = bv.x; base[h * 4 + 1] = bv.y;
      base[h * 4 + 2] = bv.z; base[h * 4 + 3] = bv.w;
      w0[h * 4 + 0] = a0.x; w0[h * 4 + 1] = a0.y; w0[h * 4 + 2] = a0.z; w0[h * 4 + 3] = a0.w;
      w1v[h * 4 + 0] = a1.x; w1v[h * 4 + 1] = a1.y; w1v[h * 4 + 2] = a1.z; w1v[h * 4 + 3] = a1.w;
    }
#pragma unroll
    for (int j = 0; j < 8; ++j) base[j] += bf2f(yh[j]);
#pragma unroll
    for (int k = 0; k < 4; ++k) {
      u16x8 yc = {0, 0, 0, 0, 0, 0, 0, 0};
      if (cis[k] >= 0) yc = *(const u16x8*)(Ycell + (size_t)cis[k] * 1024 + col);
      u16x8 o;
#pragma unroll
      for (int j = 0; j < 8; ++j)
        o[j] = f2bf(fmaxf(base[j] + bf2f(yc[j]) + ry[k] * w0[j] + rx[k] * w1v[j], 0.f));
      *(u16x8*)(A1 + (size_t)((p << 2) + k) * 1024 + col) = o;
    }
  }
}

// ---------------------------------------------------------------------------
// prep_all: all transposed bf16 weights in one dispatch.
// ---------------------------------------------------------------------------
__global__ __launch_bounds__(256)
void prep_all(const float* __restrict__ w1, const float* __restrict__ w2,
              const float* __restrict__ w3, const float* __restrict__ w4,
              u16* __restrict__ W1hrT, u16* __restrict__ W1cellT,
              u16* __restrict__ W2T, u16* __restrict__ W3T, u16* __restrict__ W4T)
{
  const int idx = blockIdx.x * 256 + threadIdx.x;
  if (idx < 131072) {
    const int n = idx >> 7, k = idx & 127;
    W1hrT[idx] = f2bf(w1[(128 + k) * 1024 + n] + w1[(256 + k) * 1024 + n]);
  } else if (idx < 393216) {
    const int i = idx - 131072;
    const int n = i >> 8, k = i & 255;
    W1cellT[i] = f2bf((k < 128) ? w1[k * 1024 + n] : w1[(128 + k) * 1024 + n]);
  } else if (idx < 917504) {
    const int i = idx - 393216;
    const int n = i >> 10, k = i & 1023;
    W2T[i] = f2bf(w2[k * 512 + n]);
  } else if (idx < 1048576) {
    const int i = idx - 917504;
    const int n = i >> 9, k = i & 511;
    W3T[i] = f2bf(w3[k * 256 + n]);
  } else if (idx < 1081344) {
    const int i = idx - 1048576;
    const int n = i >> 8, k = i & 255;
    W4T[i] = f2bf(w4[k * 128 + n]);
  }
}

// ---------------------------------------------------------------------------
extern "C" void kernel_launch(void* const* d_in, const int* in_sizes, int n_in,
                              void* d_out, int out_size, void* d_ws, size_t ws_size,
                              hipStream_t stream)
{
  const float* feat  = (const float*)d_in[0];
  const float* coord = (const float*)d_in[1];
  const float* hrg   = (const float*)d_in[2];
  const float* lrg   = (const float*)d_in[3];
  const float* w1 = (const float*)d_in[4];
  const float* b1 = (const float*)d_in[5];
  const float* w2 = (const float*)d_in[6];
  const float* b2 = (const float*)d_in[7];
  const float* w3 = (const float*)d_in[8];
  const float* b3 = (const float*)d_in[9];
  const float* w4 = (const float*)d_in[10];
  const float* b4 = (const float*)d_in[11];
  const float* w5 = (const float*)d_in[12];
  const float* b5 = (const float*)d_in[13];
  float* out = (float*)d_out;

  char* base = (char*)d_ws;
  u16* W1hrT   = (u16*)base;                       // [1024][128]
  u16* W1cellT = W1hrT + 1024 * 128;               // [1024][256]
  u16* W2T     = W1cellT + 1024 * 256;             // [512][1024]
  u16* W3T     = W2T + 512 * 1024;                 // [256][512]
  u16* W4T     = W3T + 256 * 512;                  // [128][256]
  u16* Xcell   = W4T + 128 * 256;                  // [8192][256]
  u16* Ycell   = Xcell + 8192 * 256;               // [8192][1024] bf16
  u16* Xhr     = Ycell + (size_t)8192 * 1024;      // [131072][128]
  float* relb  = (float*)(Xhr + (size_t)131072 * 128); // [131072][4][2]
  int* cellidx = (int*)(relb + (size_t)131072 * 8);    // [131072][4]
  char* chunk_base = (char*)(cellidx + (size_t)131072 * 4);
  const size_t fixed = (size_t)(chunk_base - base);

  const int NP = 131072;
  // per-pixel chunk bytes: Yhr/A3 2048 + A1 8192 + A2 4096 = 14336 (A3 aliases Yhr)
  int nc = 1;
  while (nc < 128 && fixed + (size_t)(NP / nc) * 14336ULL > ws_size) nc <<= 1;
  const int CP = NP / nc;
  const int R = CP * 4;

  u16* Yhr = (u16*)chunk_base;          // [CP][1024] bf16 ; later A3 [R][256] bf16
  u16* A1  = Yhr + (size_t)CP * 1024;   // [R][1024] bf16
  u16* A2  = A1 + (size_t)R * 1024;     // [R][512] bf16
  u16* A3  = Yhr;                       // alias (Yhr dead after expand_a1)

  prep_all<<<4224, 256, 0, stream>>>(w1, w2, w3, w4, W1hrT, W1cellT, W2T, W3T, W4T);
  gather_hr<<<NP / 64, 256, 0, stream>>>(coord, hrg, Xhr, cellidx, relb);
  prep_cells<<<8192 / 64, 256, 0, stream>>>(feat, lrg, Xcell);
  // Ycell = Xcell @ W1cellT^T (raw bf16)
  gemm_bt<3><<<(8192 / 128) * (1024 / 128), 256, 0, stream>>>(
      Xcell, W1cellT, (void*)Ycell, nullptr, 8192, 1024, 256,
      nullptr, nullptr, nullptr, 0);

  for (int ch = 0; ch < nc; ++ch) {
    const int gp0 = ch * CP;
    // Yhr = Xhr_chunk @ W1hrT^T (raw bf16)
    gemm_bt<3><<<(CP / 128) * (1024 / 128), 256, 0, stream>>>(
        Xhr + (size_t)gp0 * 128, W1hrT, (void*)Yhr, nullptr, CP, 1024, 128,
        nullptr, nullptr, nullptr, 0);
    expand_a1<<<CP / 4, 256, 0, stream>>>(
        Yhr, Ycell, b1, w1 + 384 * 1024, cellidx, relb, A1, gp0);
    gemm_bt<0><<<(R / 128) * (512 / 128), 256, 0, stream>>>(
        A1, W2T, (void*)A2, b2, R, 512, 1024, nullptr, nullptr, nullptr, 0);
    gemm_bt<0><<<(R / 128) * (256 / 128), 256, 0, stream>>>(
        A2, W3T, (void*)A3, b3, R, 256, 512, nullptr, nullptr, nullptr, 0);
    gemm_bt<2><<<(R / 128) * (128 / 128), 256, 0, stream>>>(
        A3, W4T, nullptr, b4, R, 128, 256, w5, b5, out, gp0);
  }
}

// Round 9
// 1655.419 us; speedup vs baseline: 1.3221x; 1.0664x over previous
//
#include <hip/hip_runtime.h>

// JIIF fused pipeline v9 = v8 + tail34 (layers 3+4+5 fused, 256-thread design).
// z1 = relu( Yhr[pixel] + Ycell[cell(pixel,k)] + rel*w1rel + b1 )
//   Yhr  = hr_guide_row @ (W1[128:256]+W1[256:384])   (per pixel, bf16 GEMM)
//   Ycell= [feat | -lr] @ W1[[0:128],[256:384]]        (per low-res cell, bf16)
// Layer-2 bf16 GEMM (128x128); tail34: layer-3 (64x256 tile, full N) -> A3 in
// LDS slabs -> layer-4 MFMA -> layer-5 dot + softmax blend. A3 never in HBM.
// NOTES:
//  - R4/R5: 512-thread fused tail spilled (VGPR pinned 60, 556 MB scratch
//    writes) regardless of launch_bounds. This 256-thread version keeps the
//    proven gemm_bt register budget (acc3 dies before acc4 peaks).
//  - R7: layer-2 at BN=256 regressed 52->95 us (occupancy collapse). BN=128.

typedef unsigned short u16;
typedef unsigned int   u32;
typedef __bf16  bf16x8 __attribute__((ext_vector_type(8)));
typedef float   f32x4  __attribute__((ext_vector_type(4)));
typedef unsigned short u16x8 __attribute__((ext_vector_type(8)));

__device__ __forceinline__ u16 f2bf(float f) {
  u32 u = __float_as_uint(f);
  u32 r = (u + 0x7FFFu + ((u >> 16) & 1u)) >> 16;   // RNE
  return (u16)r;
}
__device__ __forceinline__ float bf2f(u16 v) {
  return __uint_as_float(((u32)v) << 16);
}
__device__ __forceinline__ void gload_lds16(const void* g, void* l) {
  __builtin_amdgcn_global_load_lds(
      (const __attribute__((address_space(1))) void*)g,
      (__attribute__((address_space(3))) void*)l, 16, 0, 0);
}

// ---------------------------------------------------------------------------
// gather_hr: per-pixel Xhr row (q_guide_hr, bf16[128]) + cellidx[pix][4] + rel[pix][4][2]
// ---------------------------------------------------------------------------
__global__ __launch_bounds__(256)
void gather_hr(const float* __restrict__ coord, const float* __restrict__ hr,
               u16* __restrict__ Xhr, int* __restrict__ cellidx, float* __restrict__ rel)
{
  __shared__ u16 hrT[64 * 130];
  __shared__ int nhrS[64];

  const int tid = threadIdx.x;
  const int pb  = blockIdx.x << 6;        // global pixel base
  const int b   = pb >> 16;
  const int n0  = pb & 65535;
  const float rh = 0.015625f;             // 1/64

  if (tid < 64) {
    const int n = n0 + tid;
    const float cy = coord[(size_t)(b * 65536 + n) * 2 + 0];
    const float cx = coord[(size_t)(b * 65536 + n) * 2 + 1];
    float fyh = (cy + 1.0f) * 128.0f - 0.5f;
    float fxh = (cx + 1.0f) * 128.0f - 0.5f;
    int iyh = (int)floorf(fyh + 0.5f);
    int ixh = (int)floorf(fxh + 0.5f);
    bool vh = (iyh >= 0 && iyh < 256 && ixh >= 0 && ixh < 256);
    nhrS[tid] = vh ? ((iyh << 8) + ixh) : -1;
#pragma unroll
    for (int k = 0; k < 4; ++k) {
      const float vx = (k < 2) ? -1.0f : 1.0f;
      const float vy = (k & 1) ? 1.0f : -1.0f;
      const float cyk = cy + vx * rh;
      const float cxk = cx + vy * rh;
      float fy = (cyk + 1.0f) * 32.0f - 0.5f;
      float fx = (cxk + 1.0f) * 32.0f - 0.5f;
      int iy = (int)floorf(fy + 0.5f);
      int ix = (int)floorf(fx + 0.5f);
      bool valid = (iy >= 0 && iy < 64 && ix >= 0 && ix < 64);
      int iyc = min(max(iy, 0), 63);
      int ixc = min(max(ix, 0), 63);
      float qy = valid ? ((-1.0f + rh) + (2.0f * rh) * (float)iyc) : 0.0f;
      float qx = valid ? ((-1.0f + rh) + (2.0f * rh) * (float)ixc) : 0.0f;
      const int p4 = ((pb + tid) << 2) + k;
      rel[2 * p4 + 0] = (cy - qy) * 64.0f;
      rel[2 * p4 + 1] = (cx - qx) * 64.0f;
      cellidx[p4] = valid ? (b * 4096 + iyc * 64 + ixc) : -1;
    }
  }
  __syncthreads();

  const size_t hb = (size_t)b * 128 * 65536;
  for (int e = tid; e < 64 * 128; e += 256) {
    const int pix = e & 63, c = e >> 6;
    const int n = nhrS[pix];
    const float v = (n >= 0) ? hr[hb + (size_t)c * 65536 + n] : 0.0f;
    hrT[pix * 130 + c] = f2bf(v);
  }
  __syncthreads();

  for (int e = tid; e < 64 * 128; e += 256) {
    const int pix = e >> 7, c = e & 127;
    Xhr[(size_t)(pb + pix) * 128 + c] = hrT[pix * 130 + c];
  }
}

// ---------------------------------------------------------------------------
// prep_cells: Xcell[cell][0:128]=feat, [128:256]=-lr  (bf16)
// ---------------------------------------------------------------------------
__global__ __launch_bounds__(256)
void prep_cells(const float* __restrict__ feat, const float* __restrict__ lr,
                u16* __restrict__ Xcell)
{
  __shared__ u16 t[64 * 258];
  const int tid = threadIdx.x;
  const int cb = blockIdx.x << 6;
  const int b = cb >> 12;
  const int local = cb & 4095;
  const size_t fb = (size_t)b * 128 * 4096;
  for (int e = tid; e < 64 * 128; e += 256) {
    const int cell = e & 63, c = e >> 6;
    const size_t idx = fb + (size_t)c * 4096 + local + cell;
    t[cell * 258 + c]       = f2bf(feat[idx]);
    t[cell * 258 + 128 + c] = (u16)(f2bf(lr[idx]) ^ 0x8000u);
  }
  __syncthreads();
  for (int e = tid; e < 64 * 256; e += 256) {
    const int cell = e >> 8, c = e & 255;
    Xcell[(size_t)(cb + cell) * 256 + c] = t[cell * 258 + c];
  }
}

// ---------------------------------------------------------------------------
// bf16 MFMA GEMM; BK=64 via two 32-k LDS slabs; 128x128 tile.
// MODE 0: C bf16 = relu(A@B^T + bias);  MODE 3: C bf16 = A@B^T (raw)
// ---------------------------------------------------------------------------
template<int MODE>
__global__ __launch_bounds__(256)
void gemm_bt(const u16* __restrict__ A, const u16* __restrict__ BT,
             void* __restrict__ Cout, const float* __restrict__ bias,
             int M, int N, int K)
{
  __shared__ __align__(16) u16 sh[16384];
  u16* As = sh;
  u16* Bs = sh + 8192;

  const int tid = threadIdx.x;
  const int w = tid >> 6;
  const int lane = tid & 63;
  const int ntn = N >> 7;
  const int nmt = M >> 7;
  int bm, bn;
  if ((nmt & 7) == 0) {
    const int xcd = blockIdx.x & 7;
    const int t = blockIdx.x >> 3;
    bn = t % ntn;
    bm = xcd * (nmt >> 3) + t / ntn;
  } else {
    bm = blockIdx.x / ntn;
    bn = blockIdx.x - bm * ntn;
  }
  const int m0 = bm << 7, n0 = bn << 7;

  const int lrow = tid >> 2;
  const int cc   = tid & 3;
  const int gcol = (cc ^ ((lrow >> 1) & 3)) << 3;

  f32x4 acc[4][4];
#pragma unroll
  for (int ii = 0; ii < 4; ++ii)
#pragma unroll
    for (int jj = 0; jj < 4; ++jj)
      acc[ii][jj] = f32x4{0.f, 0.f, 0.f, 0.f};

  const int mbase = (w & 1) << 6;
  const int nbase = (w >> 1) << 6;
  const int fr = lane & 15;
  const int fq = lane >> 4;
  const int rchunk = (fq ^ ((fr >> 1) & 3)) << 3;

  for (int kt = 0; kt < K; kt += 64) {
#pragma unroll
    for (int s = 0; s < 2; ++s) {
      const int kb = kt + (s << 5);
#pragma unroll
      for (int q = 0; q < 2; ++q) {
        const int mrow = (q << 6) + lrow;
        gload_lds16(A + (size_t)(m0 + mrow) * K + (kb + gcol),
                    (char*)As + (s << 13) + (q << 12) + (w << 10));
        gload_lds16(BT + (size_t)(n0 + mrow) * K + (kb + gcol),
                    (char*)Bs + (s << 13) + (q << 12) + (w << 10));
      }
    }
    __syncthreads();
#pragma unroll
    for (int s = 0; s < 2; ++s) {
      const int so = s << 12;
      bf16x8 af[4], bfv[4];
#pragma unroll
      for (int ii = 0; ii < 4; ++ii) {
        af[ii]  = *(const bf16x8*)(As + so + ((mbase + (ii << 4) + fr) << 5) + rchunk);
        bfv[ii] = *(const bf16x8*)(Bs + so + ((nbase + (ii << 4) + fr) << 5) + rchunk);
      }
#pragma unroll
      for (int ii = 0; ii < 4; ++ii)
#pragma unroll
        for (int jj = 0; jj < 4; ++jj)
          acc[ii][jj] = __builtin_amdgcn_mfma_f32_16x16x32_bf16(af[ii], bfv[jj], acc[ii][jj], 0, 0, 0);
    }
    __syncthreads();
  }

#pragma unroll
  for (int jj = 0; jj < 4; ++jj) {
    const int ncol = n0 + nbase + (jj << 4) + fr;
    const float bi = (MODE == 0) ? bias[ncol] : 0.f;
#pragma unroll
    for (int ii = 0; ii < 4; ++ii) {
#pragma unroll
      for (int r = 0; r < 4; ++r) {
        const int mrow = m0 + mbase + (ii << 4) + (fq << 2) + r;
        if (MODE == 0) {
          ((u16*)Cout)[(size_t)mrow * N + ncol] = f2bf(fmaxf(acc[ii][jj][r] + bi, 0.f));
        } else {
          ((u16*)Cout)[(size_t)mrow * N + ncol] = f2bf(acc[ii][jj][r]);
        }
      }
    }
  }
}

// ---------------------------------------------------------------------------
// tail34: layers 3+4+5 for a 64-row block (16 pixels), 256 threads / 4 waves.
//   layer-3: 64x256 tile (full N3), waves split N: wave w owns cols [w*64, w*64+64)
//   A3 = relu(acc3+b3) -> 8 LDS slabs (64x32, MFMA-A-frag swizzled layout)
//   layer-4: K=256 from A3 slabs, W4 staged in 16 KB pairs; wave w owns cols [w*32,..)
//   layer-5: relu(acc4+b4) tile -> per-pixel dot w5 + softmax blend -> out
// ---------------------------------------------------------------------------
__global__ __launch_bounds__(256)
void tail34(const u16* __restrict__ A2, const u16* __restrict__ W3T,
            const u16* __restrict__ W4T, const float* __restrict__ b3,
            const float* __restrict__ b4, const float* __restrict__ w5,
            const float* __restrict__ b5, float* __restrict__ outp,
            int M, int gp0)
{
  __shared__ __align__(16) u16 sh[24576];   // 48 KB
  u16* As  = sh;            // L3 A staging: 2 slabs x (64x32)   [0,4096) u16
  u16* Bs  = sh + 4096;     // L3 B staging: 2 slabs x (256x32)  [4096,20480) u16
  u16* A3s = sh;            // A3 slabs: 8 x (64x32) [0,16384) u16 (aliases As/Bs)
  u16* W4s = sh + 16384;    // W4 staging: 2 slabs x (128x32) [16384,24576) u16
  // blend tile 64x136 aliases sh[0,8704) after layer-4.

  const int tid = threadIdx.x;
  const int w = tid >> 6;
  const int lane = tid & 63;
  const int nmt = M >> 6;
  int bm;
  if ((nmt & 7) == 0) bm = (blockIdx.x & 7) * (nmt >> 3) + (blockIdx.x >> 3);
  else bm = blockIdx.x;
  const int m0 = bm << 6;

  const int lrow = tid >> 2;                 // 0..63
  const int cc   = tid & 3;
  const int gcol = (cc ^ ((lrow >> 1) & 3)) << 3;

  const int fr = lane & 15;
  const int fq = lane >> 4;
  const int rchunk = (fq ^ ((fr >> 1) & 3)) << 3;
  const int nb3 = w << 6;                    // layer-3 wave col base

  // ---------------- layer-3 (M-tile 64, N 256, K 512) ----------------
  f32x4 acc3[4][4];
#pragma unroll
  for (int ii = 0; ii < 4; ++ii)
#pragma unroll
    for (int jj = 0; jj < 4; ++jj)
      acc3[ii][jj] = f32x4{0.f, 0.f, 0.f, 0.f};

  for (int kt = 0; kt < 512; kt += 64) {
#pragma unroll
    for (int s = 0; s < 2; ++s) {
      const int kb = kt + (s << 5);
      gload_lds16(A2 + (size_t)(m0 + lrow) * 512 + (kb + gcol),
                  (char*)As + (s << 12) + (w << 10));
#pragma unroll
      for (int q = 0; q < 4; ++q) {
        gload_lds16(W3T + (size_t)((q << 6) + lrow) * 512 + (kb + gcol),
                    (char*)Bs + (s << 14) + (q << 12) + (w << 10));
      }
    }
    __syncthreads();
#pragma unroll
    for (int s = 0; s < 2; ++s) {
      bf16x8 af[4], bfv[4];
#pragma unroll
      for (int ii = 0; ii < 4; ++ii) {
        af[ii]  = *(const bf16x8*)(As + (s << 11) + (((ii << 4) + fr) << 5) + rchunk);
        bfv[ii] = *(const bf16x8*)(Bs + (s << 13) + ((nb3 + (ii << 4) + fr) << 5) + rchunk);
      }
#pragma unroll
      for (int ii = 0; ii < 4; ++ii)
#pragma unroll
        for (int jj = 0; jj < 4; ++jj)
          acc3[ii][jj] = __builtin_amdgcn_mfma_f32_16x16x32_bf16(af[ii], bfv[jj], acc3[ii][jj], 0, 0, 0);
    }
    __syncthreads();
  }

  // ---------------- funnel: A3 = relu(acc3+b3) -> swizzled LDS slabs -------
  float b3v[4];
#pragma unroll
  for (int jj = 0; jj < 4; ++jj) b3v[jj] = b3[nb3 + (jj << 4) + fr];
#pragma unroll
  for (int jj = 0; jj < 4; ++jj) {
    const int col = nb3 + (jj << 4) + fr;
    const int sl = col >> 5, c = col & 31;
#pragma unroll
    for (int ii = 0; ii < 4; ++ii) {
#pragma unroll
      for (int r = 0; r < 4; ++r) {
        const int row = (ii << 4) + (fq << 2) + r;
        A3s[(sl << 11) + (row << 5) + (((c >> 3) ^ ((row >> 1) & 3)) << 3) + (c & 7)] =
            f2bf(fmaxf(acc3[ii][jj][r] + b3v[jj], 0.f));
      }
    }
  }

  // ---------------- layer-4 (K=256 from A3 slabs; N=128) ----------------
  f32x4 acc4[4][2];
#pragma unroll
  for (int ii = 0; ii < 4; ++ii)
#pragma unroll
    for (int jj = 0; jj < 2; ++jj)
      acc4[ii][jj] = f32x4{0.f, 0.f, 0.f, 0.f};
  const int nb4 = w << 5;

  for (int kt4 = 0; kt4 < 4; ++kt4) {
#pragma unroll
    for (int s = 0; s < 2; ++s) {
      const int kb = (kt4 << 6) + (s << 5);
#pragma unroll
      for (int q = 0; q < 2; ++q) {
        gload_lds16(W4T + (size_t)((q << 6) + lrow) * 256 + (kb + gcol),
                    (char*)W4s + (s << 13) + (q << 12) + (w << 10));
      }
    }
    __syncthreads();   // W4 visible; first iter also publishes the A3 funnel
#pragma unroll
    for (int s = 0; s < 2; ++s) {
      const int sl = (kt4 << 1) + s;
      bf16x8 af[4], bfv[2];
#pragma unroll
      for (int ii = 0; ii < 4; ++ii)
        af[ii] = *(const bf16x8*)(A3s + (sl << 11) + (((ii << 4) + fr) << 5) + rchunk);
#pragma unroll
      for (int jj = 0; jj < 2; ++jj)
        bfv[jj] = *(const bf16x8*)(W4s + (s << 12) + ((nb4 + (jj << 4) + fr) << 5) + rchunk);
#pragma unroll
      for (int ii = 0; ii < 4; ++ii)
#pragma unroll
        for (int jj = 0; jj < 2; ++jj)
          acc4[ii][jj] = __builtin_amdgcn_mfma_f32_16x16x32_bf16(af[ii], bfv[jj], acc4[ii][jj], 0, 0, 0);
    }
    __syncthreads();
  }

  // ---------------- layer-5 + softmax blend ----------------
  float b4v[2];
#pragma unroll
  for (int jj = 0; jj < 2; ++jj) b4v[jj] = b4[nb4 + (jj << 4) + fr];
#pragma unroll
  for (int ii = 0; ii < 4; ++ii) {
#pragma unroll
    for (int jj = 0; jj < 2; ++jj) {
      const int col = nb4 + (jj << 4) + fr;
#pragma unroll
      for (int r = 0; r < 4; ++r) {
        const int row = (ii << 4) + (fq << 2) + r;
        sh[row * 136 + col] = f2bf(fmaxf(acc4[ii][jj][r] + b4v[jj], 0.f));
      }
    }
  }
  const int cbase = fr << 3;
  float w50[8], w51[8];
#pragma unroll
  for (int j = 0; j < 8; ++j) {
    w50[j] = w5[((cbase + j) << 1) + 0];
    w51[j] = w5[((cbase + j) << 1) + 1];
  }
  const float b50 = b5[0], b51 = b5[1];
  __syncthreads();

#pragma unroll
  for (int rep = 0; rep < 4; ++rep) {
    const int pl = (rep << 2) + w;            // block-local pixel 0..15
    const int row = (pl << 2) + fq;           // branch k = fq
    const u16x8 v = *(const u16x8*)(sh + row * 136 + cbase);
    float s0 = 0.f, s1 = 0.f;
#pragma unroll
    for (int j = 0; j < 8; ++j) {
      const float a = bf2f(v[j]);
      s0 += a * w50[j];
      s1 += a * w51[j];
    }
#pragma unroll
    for (int off = 8; off >= 1; off >>= 1) {
      s0 += __shfl_xor(s0, off, 16);
      s1 += __shfl_xor(s1, off, 16);
    }
    float p0[4], p1[4];
#pragma unroll
    for (int k = 0; k < 4; ++k) {
      p0[k] = __shfl(s0, k << 4, 64) + b50;
      p1[k] = __shfl(s1, k << 4, 64) + b51;
    }
    if (lane == 0) {
      float mx = fmaxf(fmaxf(p1[0], p1[1]), fmaxf(p1[2], p1[3]));
      float e0 = expf(p1[0] - mx), e1 = expf(p1[1] - mx);
      float e2 = expf(p1[2] - mx), e3 = expf(p1[3] - mx);
      outp[gp0 + (m0 >> 2) + pl] =
          (p0[0] * e0 + p0[1] * e1 + p0[2] * e2 + p0[3] * e3) / (e0 + e1 + e2 + e3);
    }
  }
}

// ---------------------------------------------------------------------------
// expand_a1: wave per pixel. A1[(p*4+k)][c] = relu(Yhr[p][c] + b1[c] +
//            Ycell[cell[k]][c] + ry*w1rel0[c] + rx*w1rel1[c]); Ycell is bf16.
// ---------------------------------------------------------------------------
__global__ __launch_bounds__(256)
void expand_a1(const u16* __restrict__ Yhr, const u16* __restrict__ Ycell,
               const float* __restrict__ b1, const float* __restrict__ w1rel,
               const int* __restrict__ cellidx, const float* __restrict__ rel,
               u16* __restrict__ A1, int gp0)
{
  const int lane = threadIdx.x & 63;
  const int wv = threadIdx.x >> 6;
  const int p = (blockIdx.x << 2) + wv;        // chunk-local pixel
  const int gpix = gp0 + p;

  const int4   civ = *(const int4*)(cellidx + (size_t)gpix * 4);
  const float4 ra  = *(const float4*)(rel + (size_t)gpix * 8);
  const float4 rb  = *(const float4*)(rel + (size_t)gpix * 8 + 4);
  const int   cis[4] = {civ.x, civ.y, civ.z, civ.w};
  const float ry[4]  = {ra.x, ra.z, rb.x, rb.z};
  const float rx[4]  = {ra.y, ra.w, rb.y, rb.w};

#pragma unroll
  for (int s = 0; s < 2; ++s) {
    const int col = (s << 9) + (lane << 3);    // 8 cols per lane
    const u16x8 yh = *(const u16x8*)(Yhr + (size_t)p * 1024 + col);
    float base[8], w0[8], w1v[8];
#pragma unroll
    for (int h = 0; h < 2; ++h) {
      const float4 bv = *(const float4*)(b1 + col + (h << 2));
      const float4 a0 = *(const float4*)(w1rel + col + (h << 2));
      const float4 a1 = *(const float4*)(w1rel + 1024 + col + (h << 2));
      base[h * 4 + 0] = bv.x; base[h * 4 + 1] = bv.y;
      base[h * 4 + 2] = bv.z; base[h * 4 + 3] = bv.w;
      w0[h * 4 + 0] = a0.x; w0[h * 4 + 1] = a0.y; w0[h * 4 + 2] = a0.z; w0[h * 4 + 3] = a0.w;
      w1v[h * 4 + 0] = a1.x; w1v[h * 4 + 1] = a1.y; w1v[h * 4 + 2] = a1.z; w1v[h * 4 + 3] = a1.w;
    }
#pragma unroll
    for (int j = 0; j < 8; ++j) base[j] += bf2f(yh[j]);
#pragma unroll
    for (int k = 0; k < 4; ++k) {
      u16x8 yc = {0, 0, 0, 0, 0, 0, 0, 0};
      if (cis[k] >= 0) yc = *(const u16x8*)(Ycell + (size_t)cis[k] * 1024 + col);
      u16x8 o;
#pragma unroll
      for (int j = 0; j < 8; ++j)
        o[j] = f2bf(fmaxf(base[j] + bf2f(yc[j]) + ry[k] * w0[j] + rx[k] * w1v[j], 0.f));
      *(u16x8*)(A1 + (size_t)((p << 2) + k) * 1024 + col) = o;
    }
  }
}

// ---------------------------------------------------------------------------
// prep_all: all transposed bf16 weights in one dispatch.
// ---------------------------------------------------------------------------
__global__ __launch_bounds__(256)
void prep_all(const float* __restrict__ w1, const float* __restrict__ w2,
              const float* __restrict__ w3, const float* __restrict__ w4,
              u16* __restrict__ W1hrT, u16* __restrict__ W1cellT,
              u16* __restrict__ W2T, u16* __restrict__ W3T, u16* __restrict__ W4T)
{
  const int idx = blockIdx.x * 256 + threadIdx.x;
  if (idx < 131072) {
    const int n = idx >> 7, k = idx & 127;
    W1hrT[idx] = f2bf(w1[(128 + k) * 1024 + n] + w1[(256 + k) * 1024 + n]);
  } else if (idx < 393216) {
    const int i = idx - 131072;
    const int n = i >> 8, k = i & 255;
    W1cellT[i] = f2bf((k < 128) ? w1[k * 1024 + n] : w1[(128 + k) * 1024 + n]);
  } else if (idx < 917504) {
    const int i = idx - 393216;
    const int n = i >> 10, k = i & 1023;
    W2T[i] = f2bf(w2[k * 512 + n]);
  } else if (idx < 1048576) {
    const int i = idx - 917504;
    const int n = i >> 9, k = i & 511;
    W3T[i] = f2bf(w3[k * 256 + n]);
  } else if (idx < 1081344) {
    const int i = idx - 1048576;
    const int n = i >> 8, k = i & 255;
    W4T[i] = f2bf(w4[k * 128 + n]);
  }
}

// ---------------------------------------------------------------------------
extern "C" void kernel_launch(void* const* d_in, const int* in_sizes, int n_in,
                              void* d_out, int out_size, void* d_ws, size_t ws_size,
                              hipStream_t stream)
{
  const float* feat  = (const float*)d_in[0];
  const float* coord = (const float*)d_in[1];
  const float* hrg   = (const float*)d_in[2];
  const float* lrg   = (const float*)d_in[3];
  const float* w1 = (const float*)d_in[4];
  const float* b1 = (const float*)d_in[5];
  const float* w2 = (const float*)d_in[6];
  const float* b2 = (const float*)d_in[7];
  const float* w3 = (const float*)d_in[8];
  const float* b3 = (const float*)d_in[9];
  const float* w4 = (const float*)d_in[10];
  const float* b4 = (const float*)d_in[11];
  const float* w5 = (const float*)d_in[12];
  const float* b5 = (const float*)d_in[13];
  float* out = (float*)d_out;

  char* base = (char*)d_ws;
  u16* W1hrT   = (u16*)base;                       // [1024][128]
  u16* W1cellT = W1hrT + 1024 * 128;               // [1024][256]
  u16* W2T     = W1cellT + 1024 * 256;             // [512][1024]
  u16* W3T     = W2T + 512 * 1024;                 // [256][512]
  u16* W4T     = W3T + 256 * 512;                  // [128][256]
  u16* Xcell   = W4T + 128 * 256;                  // [8192][256]
  u16* Ycell   = Xcell + 8192 * 256;               // [8192][1024] bf16
  u16* Xhr     = Ycell + (size_t)8192 * 1024;      // [131072][128]
  float* relb  = (float*)(Xhr + (size_t)131072 * 128); // [131072][4][2]
  int* cellidx = (int*)(relb + (size_t)131072 * 8);    // [131072][4]
  char* chunk_base = (char*)(cellidx + (size_t)131072 * 4);
  const size_t fixed = (size_t)(chunk_base - base);

  const int NP = 131072;
  // per-pixel chunk bytes: Yhr 2048 + A1 8192 + A2 4096 = 14336
  int nc = 1;
  while (nc < 128 && fixed + (size_t)(NP / nc) * 14336ULL > ws_size) nc <<= 1;
  const int CP = NP / nc;
  const int R = CP * 4;

  u16* Yhr = (u16*)chunk_base;          // [CP][1024] bf16
  u16* A1  = Yhr + (size_t)CP * 1024;   // [R][1024] bf16
  u16* A2  = A1 + (size_t)R * 1024;     // [R][512] bf16

  prep_all<<<4224, 256, 0, stream>>>(w1, w2, w3, w4, W1hrT, W1cellT, W2T, W3T, W4T);
  gather_hr<<<NP / 64, 256, 0, stream>>>(coord, hrg, Xhr, cellidx, relb);
  prep_cells<<<8192 / 64, 256, 0, stream>>>(feat, lrg, Xcell);
  // Ycell = Xcell @ W1cellT^T (raw bf16)
  gemm_bt<3><<<(8192 / 128) * (1024 / 128), 256, 0, stream>>>(
      Xcell, W1cellT, (void*)Ycell, nullptr, 8192, 1024, 256);

  for (int ch = 0; ch < nc; ++ch) {
    const int gp0 = ch * CP;
    // Yhr = Xhr_chunk @ W1hrT^T (raw bf16)
    gemm_bt<3><<<(CP / 128) * (1024 / 128), 256, 0, stream>>>(
        Xhr + (size_t)gp0 * 128, W1hrT, (void*)Yhr, nullptr, CP, 1024, 128);
    expand_a1<<<CP / 4, 256, 0, stream>>>(
        Yhr, Ycell, b1, w1 + 384 * 1024, cellidx, relb, A1, gp0);
    gemm_bt<0><<<(R / 128) * (512 / 128), 256, 0, stream>>>(
        A1, W2T, (void*)A2, b2, R, 512, 1024);
    tail34<<<R / 64, 256, 0, stream>>>(
        A2, W3T, W4T, b3, b4, w5, b5, out, R, gp0);
  }
}